// Round 6
// baseline (297.865 us; speedup 1.0000x reference)
//
#include <hip/hip_runtime.h>
#include <hip/hip_bf16.h>
#include <stdint.h>

// Problem constants (fixed by setup_inputs)
#define Bn 64
#define Sn 2048
#define Dn 768
#define An 256
#define EPSF 1e-7f
#define ROWS 32               // s-rows per chunk
#define NCHUNK (Sn / ROWS)    // 64 chunks per batch
#define NK (Dn / 32)          // 24 K-steps of 32

typedef __bf16 bf16x8 __attribute__((ext_vector_type(8)));
typedef float f32x4 __attribute__((ext_vector_type(4)));

// ---------------- pack W (fp32 row-major DxA) -> bf16 MFMA-B-fragment layout ----
// packed[( (kk*16 + cb)*64 + lane )*8 + e] = bf16( W[kk*32 + (lane>>4)*8 + e][cb*16 + (lane&15)] )
__global__ void pack_w_kernel(const float* __restrict__ W, unsigned short* __restrict__ pw) {
  int kk = blockIdx.x >> 4;     // 0..23
  int cb = blockIdx.x & 15;     // 0..15
  int l  = threadIdx.x;         // 0..63
  int a  = cb * 16 + (l & 15);
  int k0 = kk * 32 + (l >> 4) * 8;
  bf16x8 pk;
#pragma unroll
  for (int j = 0; j < 8; ++j) pk[j] = (__bf16)W[(k0 + j) * An + a];
  *(bf16x8*)(pw + ((size_t)((kk * 16 + cb) * 64 + l)) * 8) = pk;
}

// ---------------- main fused kernel: direct-from-global streaming ----------------
// 2048 blocks (one 32-row chunk each), 256 threads = 4 waves, 4 blocks/CU
// (VGPR-capped at 128; LDS ~1KB). NO x LDS staging, NO prefetch, NO K-loop
// barriers: each wave loads its A-fragments straight from global fp32
// (lane pattern is 128B-line coalesced: 16 rows x 128B per instruction),
// converts to bf16 in-register, streams W B-frags from L2. Every vmcnt wait
// is for immediately-needed data -> latency hidden by 16 independent
// waves/CU (pure TLP), HBM stream continuous chip-wide.
__launch_bounds__(256, 4)
__global__ void attn_pool_main(const float* __restrict__ x,
                               const unsigned short* __restrict__ pw,
                               const float* __restrict__ bias,
                               const float* __restrict__ u,
                               const int* __restrict__ mask,
                               float* __restrict__ outpart,
                               float* __restrict__ sumpart) {
  __shared__ float aitp[128];   // [4 waves][32 rows]
  __shared__ float aitv[32];

  const int tid  = threadIdx.x;
  const int lane = tid & 63;
  const int w    = tid >> 6;      // wave 0..3, owns cols w*64..w*64+63
  const int cid  = blockIdx.x;    // chunk id 0..2047
  const int b    = cid >> 6;
  const int s0   = (cid & 63) * ROWS;

  const float* xb = x + ((size_t)b * Sn + s0) * Dn;

  const int arow  = lane & 15;     // row within 16-row block
  const int khalf = lane >> 4;     // 0..3, 8-k subgroup
  const char* wlane = (const char*)pw + (size_t)(w * 4) * 1024 + (size_t)lane * 16;

  float mval = 0.f;
  if (tid < 32) mval = (float)mask[(size_t)b * Sn + s0 + tid];

  // ---- K-loop: A direct from global fp32 -> bf16 regs; W from L2 ----
  f32x4 acc[2][4];
#pragma unroll
  for (int p = 0; p < 2; ++p)
#pragma unroll
    for (int q = 0; q < 4; ++q) acc[p][q] = (f32x4){0.f, 0.f, 0.f, 0.f};

  const float* arow0 = xb + (size_t)arow * Dn + khalf * 8;          // rows 0..15
  const float* arow1 = xb + (size_t)(arow + 16) * Dn + khalf * 8;   // rows 16..31

#pragma unroll 4
  for (int kk = 0; kk < NK; ++kk) {
    const float4* p0 = (const float4*)(arow0 + kk * 32);
    const float4* p1 = (const float4*)(arow1 + kk * 32);
    float4 r0a = p0[0], r0b = p0[1];
    float4 r1a = p1[0], r1b = p1[1];
    bf16x8 a0, a1;
    a0[0] = (__bf16)r0a.x; a0[1] = (__bf16)r0a.y; a0[2] = (__bf16)r0a.z; a0[3] = (__bf16)r0a.w;
    a0[4] = (__bf16)r0b.x; a0[5] = (__bf16)r0b.y; a0[6] = (__bf16)r0b.z; a0[7] = (__bf16)r0b.w;
    a1[0] = (__bf16)r1a.x; a1[1] = (__bf16)r1a.y; a1[2] = (__bf16)r1a.z; a1[3] = (__bf16)r1a.w;
    a1[4] = (__bf16)r1b.x; a1[5] = (__bf16)r1b.y; a1[6] = (__bf16)r1b.z; a1[7] = (__bf16)r1b.w;

    const char* wk = wlane + (size_t)kk * 16384;
    bf16x8 bfr0 = *(const bf16x8*)(wk);
    bf16x8 bfr1 = *(const bf16x8*)(wk + 1024);
    bf16x8 bfr2 = *(const bf16x8*)(wk + 2048);
    bf16x8 bfr3 = *(const bf16x8*)(wk + 3072);
    acc[0][0] = __builtin_amdgcn_mfma_f32_16x16x32_bf16(a0, bfr0, acc[0][0], 0, 0, 0);
    acc[1][0] = __builtin_amdgcn_mfma_f32_16x16x32_bf16(a1, bfr0, acc[1][0], 0, 0, 0);
    acc[0][1] = __builtin_amdgcn_mfma_f32_16x16x32_bf16(a0, bfr1, acc[0][1], 0, 0, 0);
    acc[1][1] = __builtin_amdgcn_mfma_f32_16x16x32_bf16(a1, bfr1, acc[1][1], 0, 0, 0);
    acc[0][2] = __builtin_amdgcn_mfma_f32_16x16x32_bf16(a0, bfr2, acc[0][2], 0, 0, 0);
    acc[1][2] = __builtin_amdgcn_mfma_f32_16x16x32_bf16(a1, bfr2, acc[1][2], 0, 0, 0);
    acc[0][3] = __builtin_amdgcn_mfma_f32_16x16x32_bf16(a0, bfr3, acc[0][3], 0, 0, 0);
    acc[1][3] = __builtin_amdgcn_mfma_f32_16x16x32_bf16(a1, bfr3, acc[1][3], 0, 0, 0);
  }

  // ---- epilogue: tanh + dot with u -> per-row partials ----
  float rowp[8];
#pragma unroll
  for (int p = 0; p < 8; ++p) rowp[p] = 0.f;
#pragma unroll
  for (int cbi = 0; cbi < 4; ++cbi) {
    int col = w * 64 + cbi * 16 + arow;
    float bia = bias[col];
    float uv  = u[col];
#pragma unroll
    for (int rb = 0; rb < 2; ++rb) {
#pragma unroll
      for (int r = 0; r < 4; ++r) {
        float v = acc[rb][cbi][r] + bia;
        v = fminf(fmaxf(v, -15.f), 15.f);
        float e2 = __expf(2.f * v);
        float th = (e2 - 1.f) * __builtin_amdgcn_rcpf(e2 + 1.f);
        rowp[rb * 4 + r] += th * uv;
      }
    }
  }
#pragma unroll
  for (int m = 1; m < 16; m <<= 1)
#pragma unroll
    for (int p = 0; p < 8; ++p) rowp[p] += __shfl_xor(rowp[p], m, 64);

  if (arow == 0) {
    int rbase = khalf * 4;
#pragma unroll
    for (int rb = 0; rb < 2; ++rb)
#pragma unroll
      for (int r = 0; r < 4; ++r)
        aitp[w * 32 + rb * 16 + rbase + r] = rowp[rb * 4 + r];
  }
  __syncthreads();

  // ---- ait = exp(sum)*mask ; chunk sum ----
  if (tid < 32) {
    float s = aitp[tid] + aitp[32 + tid] + aitp[64 + tid] + aitp[96 + tid];
    float av = __expf(s) * mval;
    aitv[tid] = av;
    float t = av;
#pragma unroll
    for (int m = 1; m < 32; m <<= 1) t += __shfl_xor(t, m, 64);
    if (tid == 0) sumpart[cid] = t;
  }
  __syncthreads();

  // ---- pooling: re-read x from L2 (row-major, wave-coalesced) ----
  {
    float av[32];
#pragma unroll
    for (int r = 0; r < 32; ++r) av[r] = aitv[r];
    float* op = outpart + (size_t)cid * Dn;
#pragma unroll
    for (int j = 0; j < 3; ++j) {
      int d = tid + j * 256;
      float s = 0.f;
#pragma unroll 8
      for (int r = 0; r < 32; ++r) s += av[r] * xb[(size_t)r * Dn + d];
      op[d] = s;
    }
  }
}

// ---------------- finalize: out[b,d] = sum_c outpart / (sum_c sumpart + eps) ----
// grid = 64 b x 3 slabs of 256 d
__global__ void finalize_kernel(const float* __restrict__ outpart,
                                const float* __restrict__ sumpart,
                                float* __restrict__ out) {
  __shared__ float sh;
  int b = blockIdx.x / 3, slab = blockIdx.x % 3;
  int tid = threadIdx.x;
  if (tid < 64) {
    float v = sumpart[b * 64 + tid];
#pragma unroll
    for (int m = 1; m < 64; m <<= 1) v += __shfl_xor(v, m, 64);
    if (tid == 0) sh = v + EPSF;
  }
  __syncthreads();
  float inv = 1.0f / sh;
  int d = slab * 256 + tid;
  const float* p = outpart + (size_t)b * 64 * Dn + d;
  float s = 0.f;
#pragma unroll 8
  for (int c = 0; c < 64; ++c) s += p[(size_t)c * Dn];
  out[b * Dn + d] = s * inv;
}

extern "C" void kernel_launch(void* const* d_in, const int* in_sizes, int n_in,
                              void* d_out, int out_size, void* d_ws, size_t ws_size,
                              hipStream_t stream) {
  const float* x    = (const float*)d_in[0];
  const float* W    = (const float*)d_in[1];
  const float* bias = (const float*)d_in[2];
  const float* u    = (const float*)d_in[3];
  const int*   mask = (const int*)d_in[4];
  float* out = (float*)d_out;

  unsigned short* pw = (unsigned short*)d_ws;                      // 393216 B
  float* outpart = (float*)((char*)d_ws + 393216);                 // 64*64*768*4 = 12.58 MB
  float* sumpart = (float*)((char*)d_ws + 393216 + 12582912);      // 16 KB

  hipLaunchKernelGGL(pack_w_kernel, dim3(24 * 16), dim3(64), 0, stream, W, pw);
  hipLaunchKernelGGL(attn_pool_main, dim3(Bn * NCHUNK), dim3(256), 0, stream,
                     x, pw, bias, u, mask, outpart, sumpart);
  hipLaunchKernelGGL(finalize_kernel, dim3(Bn * 3), dim3(256), 0, stream,
                     outpart, sumpart, out);
}

// Round 7
// 297.586 us; speedup vs baseline: 1.0009x; 1.0009x over previous
//
#include <hip/hip_runtime.h>
#include <hip/hip_bf16.h>
#include <stdint.h>

// Problem constants (fixed by setup_inputs)
#define Bn 64
#define Sn 2048
#define Dn 768
#define An 256
#define EPSF 1e-7f
#define ROWS 32               // s-rows per chunk
#define NCHUNK (Sn / ROWS)    // 64 chunks per batch
#define NK (Dn / 32)          // 24 K-steps of 32
#define CPB 16                // chunks per block
#define NBLK ((Bn * NCHUNK) / CPB)   // 256 blocks == 1 per CU
#define NSTEP (2 * CPB)       // 32 half-chunk pipeline steps

typedef __bf16 bf16x8 __attribute__((ext_vector_type(8)));
typedef float f32x4 __attribute__((ext_vector_type(4)));

__device__ __forceinline__ void g2lds16(const void* g, void* l) {
  __builtin_amdgcn_global_load_lds(
      (__attribute__((address_space(1))) void*)(g),
      (__attribute__((address_space(3))) void*)(l), 16, 0, 0);
}

// ---------------- pack W (fp32 row-major DxA) -> bf16 MFMA-B-fragment layout ----
// packed[( (kk*16 + cb)*64 + lane )*8 + e] = bf16( W[kk*32 + (lane>>4)*8 + e][cb*16 + (lane&15)] )
__global__ void pack_w_kernel(const float* __restrict__ W, unsigned short* __restrict__ pw) {
  int kk = blockIdx.x >> 4;     // 0..23
  int cb = blockIdx.x & 15;     // 0..15
  int l  = threadIdx.x;         // 0..63
  int a  = cb * 16 + (l & 15);
  int k0 = kk * 32 + (l >> 4) * 8;
  bf16x8 pk;
#pragma unroll
  for (int j = 0; j < 8; ++j) pk[j] = (__bf16)W[(k0 + j) * An + a];
  *(bf16x8*)(pw + ((size_t)((kk * 16 + cb) * 64 + l)) * 8) = pk;
}

// ---------------- main: producer/consumer with DISJOINT wait counters ----------------
// 256 blocks (1/CU), 512 threads = 8 waves (2/SIMD).
// Waves 4-7 (producers): global_load_lds x fp32 -> LDS (vmcnt = x ONLY; no regs).
//   Swizzle applied to the per-lane GLOBAL source addr; LDS dest stays linear.
// Waves 0-3 (consumers): A-frags via ds_read_b128 (lgkmcnt) + cvt->bf16;
//   W B-frags from L2 (vmcnt = W ONLY). No HBM latency ever blocks a consumer.
// Chunk = two 48KB K-halves, double-buffered; one raw s_barrier per step.
__launch_bounds__(512, 2)
__global__ void attn_pool_main(const float* __restrict__ x,
                               const unsigned short* __restrict__ pw,
                               const float* __restrict__ bias,
                               const float* __restrict__ u,
                               const int* __restrict__ mask,
                               float* __restrict__ outpart,
                               float* __restrict__ sumpart) {
  __shared__ __align__(16) char xbuf[2][49152];   // half-K fp32: 32 rows x 1536B, 16B-granule XOR-swizzle
  __shared__ float aitp[128];                     // [4 consumer waves][32 rows]

  const int tid  = threadIdx.x;
  const int lane = tid & 63;
  const int wv   = tid >> 6;        // 0..7
  const int cid0 = blockIdx.x * CPB;
  const int b    = cid0 >> 6;       // constant per block
  const char* xbytes = (const char*)x + (size_t)b * Sn * 3072;

  if (wv >= 4) {
    // ======================= PRODUCER =======================
    const int ptid = tid - 256;
    // prologue: stage half-step 0 into xbuf[0]
    {
      const char* cb = xbytes + (size_t)(cid0 & 63) * ROWS * 3072;
#pragma unroll
      for (int j = 0; j < 12; ++j) {
        int unit = ptid + j * 256;          // 0..3071 granules
        int row = unit / 96, g = unit % 96;
        int si = (g * 16) ^ ((row & 7) << 4);   // inverse-swizzled SOURCE
        g2lds16(cb + (size_t)row * 3072 + si, (char*)xbuf[0] + unit * 16);
      }
      asm volatile("s_waitcnt vmcnt(0)" ::: "memory");
    }
    __builtin_amdgcn_s_barrier();
    for (int t = 0; t < NSTEP; ++t) {
      if (t + 1 < NSTEP) {
        const int th = t + 1;
        const int c  = cid0 + (th >> 1);
        const int hf = th & 1;
        const char* cb = xbytes + (size_t)(c & 63) * ROWS * 3072 + hf * 1536;
        char* lb = (char*)xbuf[th & 1];
#pragma unroll
        for (int j = 0; j < 12; ++j) {
          int unit = ptid + j * 256;
          int row = unit / 96, g = unit % 96;
          int si = (g * 16) ^ ((row & 7) << 4);
          g2lds16(cb + (size_t)row * 3072 + si, lb + unit * 16);
        }
        asm volatile("s_waitcnt vmcnt(0)" ::: "memory");   // self-paced: = HBM BW share
      }
      __builtin_amdgcn_s_barrier();
    }
    return;   // all 33 barriers matched; consumers' tail needs no more barriers
  }

  // ======================= CONSUMER =======================
  const int arow  = lane & 15;
  const int khalf = lane >> 4;
  const char* wlane = (const char*)pw + (size_t)(wv * 4) * 1024 + (size_t)lane * 16;

  __builtin_amdgcn_s_barrier();     // matches producer prologue barrier

  f32x4 acc[2][4];
  for (int t = 0; t < NSTEP; ++t) {
    const char* cbuf = (const char*)xbuf[t & 1];
    const int half = t & 1;
    const int cid  = cid0 + (t >> 1);

    if (!half) {
#pragma unroll
      for (int p = 0; p < 2; ++p)
#pragma unroll
        for (int q = 0; q < 4; ++q) acc[p][q] = (f32x4){0.f, 0.f, 0.f, 0.f};
    }

#pragma unroll 4
    for (int kkl = 0; kkl < 12; ++kkl) {
      const int kk = half * 12 + kkl;
      const int inner = kkl * 128 + khalf * 32;
      const char* p0 = cbuf + (size_t)arow * 1536;
      const char* p1 = cbuf + (size_t)(arow + 16) * 1536;
      const int sw0 = (arow & 7) << 4;
      float4 f00 = *(const float4*)(p0 + ((inner     ) ^ sw0));
      float4 f01 = *(const float4*)(p0 + ((inner + 16) ^ sw0));
      float4 f10 = *(const float4*)(p1 + ((inner     ) ^ sw0));
      float4 f11 = *(const float4*)(p1 + ((inner + 16) ^ sw0));
      bf16x8 a0, a1;
      a0[0] = (__bf16)f00.x; a0[1] = (__bf16)f00.y; a0[2] = (__bf16)f00.z; a0[3] = (__bf16)f00.w;
      a0[4] = (__bf16)f01.x; a0[5] = (__bf16)f01.y; a0[6] = (__bf16)f01.z; a0[7] = (__bf16)f01.w;
      a1[0] = (__bf16)f10.x; a1[1] = (__bf16)f10.y; a1[2] = (__bf16)f10.z; a1[3] = (__bf16)f10.w;
      a1[4] = (__bf16)f11.x; a1[5] = (__bf16)f11.y; a1[6] = (__bf16)f11.z; a1[7] = (__bf16)f11.w;

      const char* wk = wlane + (size_t)kk * 16384;
      bf16x8 bfr0 = *(const bf16x8*)(wk);
      bf16x8 bfr1 = *(const bf16x8*)(wk + 1024);
      bf16x8 bfr2 = *(const bf16x8*)(wk + 2048);
      bf16x8 bfr3 = *(const bf16x8*)(wk + 3072);
      acc[0][0] = __builtin_amdgcn_mfma_f32_16x16x32_bf16(a0, bfr0, acc[0][0], 0, 0, 0);
      acc[1][0] = __builtin_amdgcn_mfma_f32_16x16x32_bf16(a1, bfr0, acc[1][0], 0, 0, 0);
      acc[0][1] = __builtin_amdgcn_mfma_f32_16x16x32_bf16(a0, bfr1, acc[0][1], 0, 0, 0);
      acc[1][1] = __builtin_amdgcn_mfma_f32_16x16x32_bf16(a1, bfr1, acc[1][1], 0, 0, 0);
      acc[0][2] = __builtin_amdgcn_mfma_f32_16x16x32_bf16(a0, bfr2, acc[0][2], 0, 0, 0);
      acc[1][2] = __builtin_amdgcn_mfma_f32_16x16x32_bf16(a1, bfr2, acc[1][2], 0, 0, 0);
      acc[0][3] = __builtin_amdgcn_mfma_f32_16x16x32_bf16(a0, bfr3, acc[0][3], 0, 0, 0);
      acc[1][3] = __builtin_amdgcn_mfma_f32_16x16x32_bf16(a1, bfr3, acc[1][3], 0, 0, 0);
    }

    if (half) {
      // ---- epilogue: tanh + dot with u -> per-row partials into aitp ----
      float rowp[8];
#pragma unroll
      for (int p = 0; p < 8; ++p) rowp[p] = 0.f;
#pragma unroll
      for (int cbi = 0; cbi < 4; ++cbi) {
        int col = wv * 64 + cbi * 16 + arow;
        float bia = bias[col];
        float uv  = u[col];
#pragma unroll
        for (int rb = 0; rb < 2; ++rb) {
#pragma unroll
          for (int r = 0; r < 4; ++r) {
            float v = acc[rb][cbi][r] + bia;
            v = fminf(fmaxf(v, -15.f), 15.f);
            float e2 = __expf(2.f * v);
            float th = (e2 - 1.f) * __builtin_amdgcn_rcpf(e2 + 1.f);
            rowp[rb * 4 + r] += th * uv;
          }
        }
      }
#pragma unroll
      for (int m = 1; m < 16; m <<= 1)
#pragma unroll
        for (int p = 0; p < 8; ++p) rowp[p] += __shfl_xor(rowp[p], m, 64);
      if (arow == 0) {
        int rbase = khalf * 4;
#pragma unroll
        for (int rb = 0; rb < 2; ++rb)
#pragma unroll
          for (int r = 0; r < 4; ++r)
            aitp[wv * 32 + rb * 16 + rbase + r] = rowp[rb * 4 + r];
      }
      asm volatile("s_waitcnt lgkmcnt(0)" ::: "memory");
    }

    __builtin_amdgcn_s_barrier();   // step end: next half published; buffer handoff

    if (half) {
      // ---- tail (overlaps producer's next stage; touches NO x-LDS) ----
      const int s0 = (cid & 63) * ROWS;
      const int r  = lane & 31;
      float s = aitp[r] + aitp[32 + r] + aitp[64 + r] + aitp[96 + r];
      float mv = (float)mask[(size_t)b * Sn + s0 + r];
      float avr = __expf(s) * mv;
      if (wv == 0) {
        float ts = avr;
#pragma unroll
        for (int m = 1; m < 32; m <<= 1) ts += __shfl_xor(ts, m, 64);
        if (lane == 0) sumpart[cid] = ts;
      }
      float av[32];
#pragma unroll
      for (int r2 = 0; r2 < 32; ++r2) av[r2] = __shfl(avr, r2, 64);
      // pooling: re-read chunk from L2 (just streamed -> hot), coalesced
      const float* xrow = (const float*)(xbytes + (size_t)s0 * 3072);
      float* op = outpart + (size_t)cid * Dn;
#pragma unroll
      for (int j = 0; j < 3; ++j) {
        int d = tid + j * 256;
        float sa = 0.f;
#pragma unroll 8
        for (int r2 = 0; r2 < 32; ++r2) sa += av[r2] * xrow[(size_t)r2 * Dn + d];
        op[d] = sa;
      }
    }
  }
}

// ---------------- finalize: out[b,d] = sum_c outpart / (sum_c sumpart + eps) ----
// grid = 64 b x 3 slabs of 256 d
__global__ void finalize_kernel(const float* __restrict__ outpart,
                                const float* __restrict__ sumpart,
                                float* __restrict__ out) {
  __shared__ float sh;
  int b = blockIdx.x / 3, slab = blockIdx.x % 3;
  int tid = threadIdx.x;
  if (tid < 64) {
    float v = sumpart[b * 64 + tid];
#pragma unroll
    for (int m = 1; m < 64; m <<= 1) v += __shfl_xor(v, m, 64);
    if (tid == 0) sh = v + EPSF;
  }
  __syncthreads();
  float inv = 1.0f / sh;
  int d = slab * 256 + tid;
  const float* p = outpart + (size_t)b * 64 * Dn + d;
  float s = 0.f;
#pragma unroll 8
  for (int c = 0; c < 64; ++c) s += p[(size_t)c * Dn];
  out[b * Dn + d] = s * inv;
}

extern "C" void kernel_launch(void* const* d_in, const int* in_sizes, int n_in,
                              void* d_out, int out_size, void* d_ws, size_t ws_size,
                              hipStream_t stream) {
  const float* x    = (const float*)d_in[0];
  const float* W    = (const float*)d_in[1];
  const float* bias = (const float*)d_in[2];
  const float* u    = (const float*)d_in[3];
  const int*   mask = (const int*)d_in[4];
  float* out = (float*)d_out;

  unsigned short* pw = (unsigned short*)d_ws;                      // 393216 B
  float* outpart = (float*)((char*)d_ws + 393216);                 // 64*64*768*4 = 12.58 MB
  float* sumpart = (float*)((char*)d_ws + 393216 + 12582912);      // 16 KB

  hipLaunchKernelGGL(pack_w_kernel, dim3(24 * 16), dim3(64), 0, stream, W, pw);
  hipLaunchKernelGGL(attn_pool_main, dim3(NBLK), dim3(512), 0, stream,
                     x, pw, bias, u, mask, outpart, sumpart);
  hipLaunchKernelGGL(finalize_kernel, dim3(Bn * 3), dim3(256), 0, stream,
                     outpart, sumpart, out);
}

// Round 8
// 196.862 us; speedup vs baseline: 1.5131x; 1.5116x over previous
//
#include <hip/hip_runtime.h>
#include <hip/hip_bf16.h>
#include <stdint.h>

// Problem constants (fixed by setup_inputs)
#define Bn 64
#define Sn 2048
#define Dn 768
#define An 256
#define EPSF 1e-7f
#define ROWS 32              // s-rows per block
#define NCHUNK (Sn / ROWS)   // 64 chunks per batch
#define NK (Dn / 32)         // 24 K-steps of 32

typedef __bf16 bf16x4 __attribute__((ext_vector_type(4)));
typedef __bf16 bf16x8 __attribute__((ext_vector_type(8)));
typedef float f32x4 __attribute__((ext_vector_type(4)));

// ---------------- pack W (fp32 row-major DxA) -> bf16 MFMA-B-fragment layout ----
// packed[( (kk*16 + cb)*64 + lane )*8 + e] = bf16( W[kk*32 + (lane>>4)*8 + e][cb*16 + (lane&15)] )
__global__ void pack_w_kernel(const float* __restrict__ W, unsigned short* __restrict__ pw) {
  int kk = blockIdx.x >> 4;     // 0..23
  int cb = blockIdx.x & 15;     // 0..15
  int l  = threadIdx.x;         // 0..63
  int a  = cb * 16 + (l & 15);
  int k0 = kk * 32 + (l >> 4) * 8;
  bf16x8 pk;
#pragma unroll
  for (int j = 0; j < 8; ++j) pk[j] = (__bf16)W[(k0 + j) * An + a];
  *(bf16x8*)(pw + ((size_t)((kk * 16 + cb) * 64 + l)) * 8) = pk;
}

// ---------------- main fused kernel: half-chunk pipelined staging ----------------
// grid = 2048 (one 32-row chunk each), 256 threads = 4 waves, 3 blocks/CU.
// Stage rows 0-15 -> LDS(bf16, swizzled); ISSUE rows 16-31 loads (pinned by
// sched_barrier(0)) BEFORE K-loop-A, so every block keeps HBM loads in flight
// during its compute phase. K-loop-A's W-load vmcnt waits drain the half-2
// stream, but that stall is BW-paced (productive). Raw s_barrier + lgkm-only
// drains between phases -> vmcnt never drained at a barrier.
__launch_bounds__(256, 3)
__global__ void attn_pool_main(const float* __restrict__ x,
                               const unsigned short* __restrict__ pw,
                               const float* __restrict__ bias,
                               const float* __restrict__ u,
                               const int* __restrict__ mask,
                               float* __restrict__ outpart,
                               float* __restrict__ sumpart) {
  __shared__ __align__(16) char xs[49152];   // 32 rows x 768 bf16, XOR-swizzled
  __shared__ float aitp[128];
  __shared__ float aitv[32];

  const int tid  = threadIdx.x;
  const int lane = tid & 63;
  const int w    = tid >> 6;      // wave 0..3, cols w*64..w*64+63
  const int cid  = blockIdx.x;
  const int b    = cid >> 6;
  const int s0   = (cid & 63) * ROWS;
  const char* cbase = (const char*)x + ((size_t)b * Sn + s0) * 3072;

  float mval = 0.f;
  if (tid < 32) mval = (float)mask[(size_t)b * Sn + s0 + tid];

  float4 ld[12];
  // ---- issue P0: rows 0-15 (48KB contiguous) ----
#pragma unroll
  for (int j = 0; j < 12; ++j)
    ld[j] = *(const float4*)(cbase + (size_t)(tid + j * 256) * 16);
  __builtin_amdgcn_sched_barrier(0);

  // ---- cvt P0 -> LDS rows 0-15 ----
#pragma unroll
  for (int j = 0; j < 12; ++j) {
    int G = tid + j * 256;            // 16B granule, 192 per row
    int row = G / 192, cg = G % 192;
    bf16x4 pk;
    pk[0] = (__bf16)ld[j].x; pk[1] = (__bf16)ld[j].y;
    pk[2] = (__bf16)ld[j].z; pk[3] = (__bf16)ld[j].w;
    *(bf16x4*)(xs + ((row * 1536 + cg * 8) ^ ((row & 7) << 4))) = pk;
  }
  // ---- issue P1: rows 16-31 (in flight across K-loop-A) ----
#pragma unroll
  for (int j = 0; j < 12; ++j)
    ld[j] = *(const float4*)(cbase + 49152 + (size_t)(tid + j * 256) * 16);
  __builtin_amdgcn_sched_barrier(0);

  asm volatile("s_waitcnt lgkmcnt(0)" ::: "memory");
  __builtin_amdgcn_s_barrier();       // rows 0-15 published; P1 streaming

  const int arow  = lane & 15;
  const int kh16  = (lane >> 4) * 16;
  const int swz   = (arow & 7) << 4;
  const char* wlane = (const char*)pw + (size_t)(w * 4) * 1024 + (size_t)lane * 16;

  f32x4 acc[2][4];
#pragma unroll
  for (int p = 0; p < 2; ++p)
#pragma unroll
    for (int q = 0; q < 4; ++q) acc[p][q] = (f32x4){0.f, 0.f, 0.f, 0.f};

  // ---- K-loop-A: rows 0-15 ----
#pragma unroll 4
  for (int kk = 0; kk < NK; ++kk) {
    const char* wk = wlane + (size_t)kk * 16384;
    bf16x8 bfr0 = *(const bf16x8*)(wk);
    bf16x8 bfr1 = *(const bf16x8*)(wk + 1024);
    bf16x8 bfr2 = *(const bf16x8*)(wk + 2048);
    bf16x8 bfr3 = *(const bf16x8*)(wk + 3072);
    bf16x8 a0 = *(const bf16x8*)(xs + ((arow * 1536 + kk * 64 + kh16) ^ swz));
    acc[0][0] = __builtin_amdgcn_mfma_f32_16x16x32_bf16(a0, bfr0, acc[0][0], 0, 0, 0);
    acc[0][1] = __builtin_amdgcn_mfma_f32_16x16x32_bf16(a0, bfr1, acc[0][1], 0, 0, 0);
    acc[0][2] = __builtin_amdgcn_mfma_f32_16x16x32_bf16(a0, bfr2, acc[0][2], 0, 0, 0);
    acc[0][3] = __builtin_amdgcn_mfma_f32_16x16x32_bf16(a0, bfr3, acc[0][3], 0, 0, 0);
  }

  // ---- cvt P1 -> LDS rows 16-31 (vmcnt waits on P1 at first use) ----
#pragma unroll
  for (int j = 0; j < 12; ++j) {
    int G = tid + j * 256;
    int row = 16 + G / 192, cg = G % 192;
    bf16x4 pk;
    pk[0] = (__bf16)ld[j].x; pk[1] = (__bf16)ld[j].y;
    pk[2] = (__bf16)ld[j].z; pk[3] = (__bf16)ld[j].w;
    *(bf16x4*)(xs + ((row * 1536 + cg * 8) ^ ((row & 7) << 4))) = pk;
  }
  asm volatile("s_waitcnt lgkmcnt(0)" ::: "memory");
  __builtin_amdgcn_s_barrier();       // rows 16-31 published

  // ---- K-loop-B: rows 16-31 (W re-read, L2-hot) ----
#pragma unroll 4
  for (int kk = 0; kk < NK; ++kk) {
    const char* wk = wlane + (size_t)kk * 16384;
    bf16x8 bfr0 = *(const bf16x8*)(wk);
    bf16x8 bfr1 = *(const bf16x8*)(wk + 1024);
    bf16x8 bfr2 = *(const bf16x8*)(wk + 2048);
    bf16x8 bfr3 = *(const bf16x8*)(wk + 3072);
    bf16x8 a1 = *(const bf16x8*)(xs + (((arow + 16) * 1536 + kk * 64 + kh16) ^ swz));
    acc[1][0] = __builtin_amdgcn_mfma_f32_16x16x32_bf16(a1, bfr0, acc[1][0], 0, 0, 0);
    acc[1][1] = __builtin_amdgcn_mfma_f32_16x16x32_bf16(a1, bfr1, acc[1][1], 0, 0, 0);
    acc[1][2] = __builtin_amdgcn_mfma_f32_16x16x32_bf16(a1, bfr2, acc[1][2], 0, 0, 0);
    acc[1][3] = __builtin_amdgcn_mfma_f32_16x16x32_bf16(a1, bfr3, acc[1][3], 0, 0, 0);
  }

  // ---- epilogue: tanh + dot with u -> per-row partials ----
  float rowp[8];
#pragma unroll
  for (int p = 0; p < 8; ++p) rowp[p] = 0.f;
#pragma unroll
  for (int cbi = 0; cbi < 4; ++cbi) {
    int col = w * 64 + cbi * 16 + arow;
    float bia = bias[col];
    float uv  = u[col];
#pragma unroll
    for (int rb = 0; rb < 2; ++rb) {
#pragma unroll
      for (int r = 0; r < 4; ++r) {
        float v = acc[rb][cbi][r] + bia;
        v = fminf(fmaxf(v, -15.f), 15.f);
        float e2 = __expf(2.f * v);
        float th = (e2 - 1.f) * __builtin_amdgcn_rcpf(e2 + 1.f);
        rowp[rb * 4 + r] += th * uv;
      }
    }
  }
#pragma unroll
  for (int m = 1; m < 16; m <<= 1)
#pragma unroll
    for (int p = 0; p < 8; ++p) rowp[p] += __shfl_xor(rowp[p], m, 64);

  if (arow == 0) {
    int rbase = (lane >> 4) * 4;
#pragma unroll
    for (int rb = 0; rb < 2; ++rb)
#pragma unroll
      for (int r = 0; r < 4; ++r)
        aitp[w * 32 + rb * 16 + rbase + r] = rowp[rb * 4 + r];
  }
  __syncthreads();

  // ---- ait = exp(sum)*mask ; chunk sum ----
  if (tid < 32) {
    float s = aitp[tid] + aitp[32 + tid] + aitp[64 + tid] + aitp[96 + tid];
    float av = __expf(s) * mval;
    aitv[tid] = av;
    float t = av;
#pragma unroll
    for (int m = 1; m < 32; m <<= 1) t += __shfl_xor(t, m, 64);
    if (tid == 0) sumpart[cid] = t;
  }
  __syncthreads();

  // ---- pooling: per-thread scalar LDS reads, direct global write ----
  {
    float* op = outpart + (size_t)cid * Dn;
#pragma unroll
    for (int j = 0; j < 3; ++j) {
      int d = tid + j * 256;
      float s = 0.f;
#pragma unroll 8
      for (int r = 0; r < 32; ++r) {
        unsigned short hv =
            *(const unsigned short*)(xs + ((r * 1536 + d * 2) ^ ((r & 7) << 4)));
        union { unsigned int ui; float f; } cv;
        cv.ui = ((unsigned int)hv) << 16;
        s += aitv[r] * cv.f;
      }
      op[d] = s;
    }
  }
}

// ---------------- finalize: out[b,d] = sum_c outpart / (sum_c sumpart + eps) ----
// grid = 64 b x 3 slabs of 256 d
__global__ void finalize_kernel(const float* __restrict__ outpart,
                                const float* __restrict__ sumpart,
                                float* __restrict__ out) {
  __shared__ float sh;
  int b = blockIdx.x / 3, slab = blockIdx.x % 3;
  int tid = threadIdx.x;
  if (tid < 64) {
    float v = sumpart[b * 64 + tid];
#pragma unroll
    for (int m = 1; m < 64; m <<= 1) v += __shfl_xor(v, m, 64);
    if (tid == 0) sh = v + EPSF;
  }
  __syncthreads();
  float inv = 1.0f / sh;
  int d = slab * 256 + tid;
  const float* p = outpart + (size_t)b * 64 * Dn + d;
  float s = 0.f;
#pragma unroll 8
  for (int c = 0; c < 64; ++c) s += p[(size_t)c * Dn];
  out[b * Dn + d] = s * inv;
}

extern "C" void kernel_launch(void* const* d_in, const int* in_sizes, int n_in,
                              void* d_out, int out_size, void* d_ws, size_t ws_size,
                              hipStream_t stream) {
  const float* x    = (const float*)d_in[0];
  const float* W    = (const float*)d_in[1];
  const float* bias = (const float*)d_in[2];
  const float* u    = (const float*)d_in[3];
  const int*   mask = (const int*)d_in[4];
  float* out = (float*)d_out;

  unsigned short* pw = (unsigned short*)d_ws;                      // 393216 B
  float* outpart = (float*)((char*)d_ws + 393216);                 // 64*64*768*4 = 12.58 MB
  float* sumpart = (float*)((char*)d_ws + 393216 + 12582912);      // 16 KB

  hipLaunchKernelGGL(pack_w_kernel, dim3(24 * 16), dim3(64), 0, stream, W, pw);
  hipLaunchKernelGGL(attn_pool_main, dim3(Bn * NCHUNK), dim3(256), 0, stream,
                     x, pw, bias, u, mask, outpart, sumpart);
  hipLaunchKernelGGL(finalize_kernel, dim3(Bn * 3), dim3(256), 0, stream,
                     outpart, sumpart, out);
}

// Round 10
// 146.464 us; speedup vs baseline: 2.0337x; 1.3441x over previous
//
#include <hip/hip_runtime.h>
#include <hip/hip_bf16.h>
#include <stdint.h>

// Problem constants (fixed by setup_inputs)
#define Bn 64
#define Sn 2048
#define Dn 768
#define An 256
#define EPSF 1e-7f
#define ROWS 32              // s-rows per block
#define NCHUNK (Sn / ROWS)   // 64 chunks per batch
#define NK (Dn / 32)         // 24 K-steps of 32

typedef __bf16 bf16x8 __attribute__((ext_vector_type(8)));
typedef float f32x4 __attribute__((ext_vector_type(4)));

// ---------------- pack W (fp32 row-major DxA) -> bf16 MFMA-B-fragment layout ----
// packed[( (kk*16 + cb)*64 + lane )*8 + e] = bf16( W[kk*32 + (lane>>4)*8 + e][cb*16 + (lane&15)] )
__global__ void pack_w_kernel(const float* __restrict__ W, unsigned short* __restrict__ pw) {
  int kk = blockIdx.x >> 4;     // 0..23
  int cb = blockIdx.x & 15;     // 0..15
  int l  = threadIdx.x;         // 0..63
  int a  = cb * 16 + (l & 15);
  int k0 = kk * 32 + (l >> 4) * 8;
  bf16x8 pk;
#pragma unroll
  for (int j = 0; j < 8; ++j) pk[j] = (__bf16)W[(k0 + j) * An + a];
  *(bf16x8*)(pw + ((size_t)((kk * 16 + cb) * 64 + l)) * 8) = pk;
}

// ---------------- main fused kernel (R2 structure + depth-4 W register pipeline) ----
// grid = 4096 (one 32-row chunk each), 256 threads = 4 waves, 3 blocks/CU.
// Staging loop is R2's proven byte-exact code (12 units x 8 floats/thread).
// K-loop: W B-frags rotate through wf[4][4] (static indexing): use slot kk&3,
// immediately reload it for kk+4. Issue->use distance = 12 loads -> compiler
// emits counted vmcnt waits; ~220cy L2 latency hides under 3 K-steps of MFMA.
__launch_bounds__(256, 3)
__global__ void attn_pool_main(const float* __restrict__ x,
                               const unsigned short* __restrict__ pw,
                               const float* __restrict__ bias,
                               const float* __restrict__ u,
                               const int* __restrict__ mask,
                               float* __restrict__ outpart,
                               float* __restrict__ sumpart) {
  __shared__ __align__(16) char xs[49152];   // 32 rows x 768 bf16, XOR-swizzled
  __shared__ float aitp[128];
  __shared__ float aitv[32];

  const int tid  = threadIdx.x;
  const int lane = tid & 63;
  const int w    = tid >> 6;      // wave 0..3, cols w*64..w*64+63
  const int cid  = blockIdx.x;
  const int b    = cid >> 6;
  const int s0   = (cid & 63) * ROWS;

  float mval = 0.f;
  if (tid < 32) mval = (float)mask[(size_t)b * Sn + s0 + tid];

  // ---- stage x tile: 32 rows x 768 fp32 -> bf16 LDS (swizzled) [R2-proven] ----
  const float* xb = x + ((size_t)b * Sn + s0) * Dn;
#pragma unroll
  for (int j = 0; j < 12; ++j) {
    int unit = tid + j * 256;       // 0..3071 ; 8 k-elems each
    int row  = unit / 96;
    int ku   = unit % 96;
    const float4* g = (const float4*)(xb + (size_t)row * Dn + ku * 8);
    float4 v0 = g[0];
    float4 v1 = g[1];
    bf16x8 pk;
    pk[0] = (__bf16)v0.x; pk[1] = (__bf16)v0.y; pk[2] = (__bf16)v0.z; pk[3] = (__bf16)v0.w;
    pk[4] = (__bf16)v1.x; pk[5] = (__bf16)v1.y; pk[6] = (__bf16)v1.z; pk[7] = (__bf16)v1.w;
    int off = (row * 1536 + ku * 16) ^ ((row & 7) << 4);
    *(bf16x8*)(xs + off) = pk;
  }

  const int arow  = lane & 15;
  const int kh16  = (lane >> 4) * 16;
  const int swz   = (arow & 7) << 4;
  const char* wlane = (const char*)pw + (size_t)(w * 4) * 1024 + (size_t)lane * 16;

  // ---- W pipeline prologue: load kk=0..3 into wf ----
  bf16x8 wf[4][4];
#pragma unroll
  for (int s = 0; s < 4; ++s) {
    const char* wk = wlane + (size_t)s * 16384;
    wf[s][0] = *(const bf16x8*)(wk);
    wf[s][1] = *(const bf16x8*)(wk + 1024);
    wf[s][2] = *(const bf16x8*)(wk + 2048);
    wf[s][3] = *(const bf16x8*)(wk + 3072);
  }

  asm volatile("s_waitcnt lgkmcnt(0)" ::: "memory");
  __builtin_amdgcn_s_barrier();     // xs published; wf stream in flight

  f32x4 acc[2][4];
#pragma unroll
  for (int p = 0; p < 2; ++p)
#pragma unroll
    for (int q = 0; q < 4; ++q) acc[p][q] = (f32x4){0.f, 0.f, 0.f, 0.f};

  // ---- K-loop: use wf[kk&3], reload it for kk+4 (counted vmcnt waits) ----
#pragma unroll
  for (int kk = 0; kk < NK; ++kk) {
    const int s = kk & 3;
    bf16x8 a0 = *(const bf16x8*)(xs + ((arow * 1536 + kk * 64 + kh16) ^ swz));
    bf16x8 a1 = *(const bf16x8*)(xs + (((arow + 16) * 1536 + kk * 64 + kh16) ^ swz));
    bf16x8 b0 = wf[s][0], b1 = wf[s][1], b2 = wf[s][2], b3 = wf[s][3];
    if (kk + 4 < NK) {
      const char* wk = wlane + (size_t)(kk + 4) * 16384;
      wf[s][0] = *(const bf16x8*)(wk);
      wf[s][1] = *(const bf16x8*)(wk + 1024);
      wf[s][2] = *(const bf16x8*)(wk + 2048);
      wf[s][3] = *(const bf16x8*)(wk + 3072);
    }
    acc[0][0] = __builtin_amdgcn_mfma_f32_16x16x32_bf16(a0, b0, acc[0][0], 0, 0, 0);
    acc[1][0] = __builtin_amdgcn_mfma_f32_16x16x32_bf16(a1, b0, acc[1][0], 0, 0, 0);
    acc[0][1] = __builtin_amdgcn_mfma_f32_16x16x32_bf16(a0, b1, acc[0][1], 0, 0, 0);
    acc[1][1] = __builtin_amdgcn_mfma_f32_16x16x32_bf16(a1, b1, acc[1][1], 0, 0, 0);
    acc[0][2] = __builtin_amdgcn_mfma_f32_16x16x32_bf16(a0, b2, acc[0][2], 0, 0, 0);
    acc[1][2] = __builtin_amdgcn_mfma_f32_16x16x32_bf16(a1, b2, acc[1][2], 0, 0, 0);
    acc[0][3] = __builtin_amdgcn_mfma_f32_16x16x32_bf16(a0, b3, acc[0][3], 0, 0, 0);
    acc[1][3] = __builtin_amdgcn_mfma_f32_16x16x32_bf16(a1, b3, acc[1][3], 0, 0, 0);
  }

  // ---- epilogue: tanh + dot with u -> per-row partials ----
  float rowp[8];
#pragma unroll
  for (int p = 0; p < 8; ++p) rowp[p] = 0.f;
#pragma unroll
  for (int cbi = 0; cbi < 4; ++cbi) {
    int col = w * 64 + cbi * 16 + arow;
    float bia = bias[col];
    float uv  = u[col];
#pragma unroll
    for (int rb = 0; rb < 2; ++rb) {
#pragma unroll
      for (int r = 0; r < 4; ++r) {
        float v = acc[rb][cbi][r] + bia;
        v = fminf(fmaxf(v, -15.f), 15.f);
        float e2 = __expf(2.f * v);
        float th = (e2 - 1.f) * __builtin_amdgcn_rcpf(e2 + 1.f);
        rowp[rb * 4 + r] += th * uv;
      }
    }
  }
#pragma unroll
  for (int m = 1; m < 16; m <<= 1)
#pragma unroll
    for (int p = 0; p < 8; ++p) rowp[p] += __shfl_xor(rowp[p], m, 64);

  if (arow == 0) {
    int rbase = (lane >> 4) * 4;
#pragma unroll
    for (int rb = 0; rb < 2; ++rb)
#pragma unroll
      for (int r = 0; r < 4; ++r)
        aitp[w * 32 + rb * 16 + rbase + r] = rowp[rb * 4 + r];
  }
  __syncthreads();

  // ---- ait = exp(sum)*mask ; chunk sum ----
  if (tid < 32) {
    float s = aitp[tid] + aitp[32 + tid] + aitp[64 + tid] + aitp[96 + tid];
    float av = __expf(s) * mval;
    aitv[tid] = av;
    float t = av;
#pragma unroll
    for (int m = 1; m < 32; m <<= 1) t += __shfl_xor(t, m, 64);
    if (tid == 0) sumpart[cid] = t;
  }
  __syncthreads();

  // ---- pooling (R2-proven): 192 threads, 2 row-groups of 16 rows ----
  float pac[8];
#pragma unroll
  for (int e = 0; e < 8; ++e) pac[e] = 0.f;
  int rg = tid / 96;              // 0..1 for tid<192
  int du = tid % 96;              // 8-d unit
  if (tid < 192) {
#pragma unroll
    for (int rr = 0; rr < 16; ++rr) {
      int row = rg * 16 + rr;
      int off = (row * 1536 + du * 16) ^ ((row & 7) << 4);
      bf16x8 xv = *(const bf16x8*)(xs + off);
      float a = aitv[row];
#pragma unroll
      for (int e = 0; e < 8; ++e) pac[e] += a * (float)xv[e];
    }
  }
  __syncthreads();   // all xs reads done -> safe to overlay outred onto xs

  float* outred = (float*)xs;     // [2][768] overlay
  if (tid < 192) {
#pragma unroll
    for (int e = 0; e < 8; ++e) outred[rg * 768 + du * 8 + e] = pac[e];
  }
  __syncthreads();

  {
    float* op = outpart + (size_t)cid * Dn;
#pragma unroll
    for (int j = 0; j < 3; ++j) {
      int d = tid + j * 256;
      op[d] = outred[d] + outred[768 + d];
    }
  }
}

// ---------------- finalize: out[b,d] = sum_c outpart / (sum_c sumpart + eps) ----
// grid = 64 b x 3 slabs of 256 d
__global__ void finalize_kernel(const float* __restrict__ outpart,
                                const float* __restrict__ sumpart,
                                float* __restrict__ out) {
  __shared__ float sh;
  int b = blockIdx.x / 3, slab = blockIdx.x % 3;
  int tid = threadIdx.x;
  if (tid < 64) {
    float v = sumpart[b * 64 + tid];
#pragma unroll
    for (int m = 1; m < 64; m <<= 1) v += __shfl_xor(v, m, 64);
    if (tid == 0) sh = v + EPSF;
  }
  __syncthreads();
  float inv = 1.0f / sh;
  int d = slab * 256 + tid;
  const float* p = outpart + (size_t)b * 64 * Dn + d;
  float s = 0.f;
#pragma unroll 8
  for (int c = 0; c < 64; ++c) s += p[(size_t)c * Dn];
  out[b * Dn + d] = s * inv;
}

extern "C" void kernel_launch(void* const* d_in, const int* in_sizes, int n_in,
                              void* d_out, int out_size, void* d_ws, size_t ws_size,
                              hipStream_t stream) {
  const float* x    = (const float*)d_in[0];
  const float* W    = (const float*)d_in[1];
  const float* bias = (const float*)d_in[2];
  const float* u    = (const float*)d_in[3];
  const int*   mask = (const int*)d_in[4];
  float* out = (float*)d_out;

  unsigned short* pw = (unsigned short*)d_ws;                      // 393216 B
  float* outpart = (float*)((char*)d_ws + 393216);                 // 64*64*768*4 = 12.58 MB
  float* sumpart = (float*)((char*)d_ws + 393216 + 12582912);      // 16 KB

  hipLaunchKernelGGL(pack_w_kernel, dim3(24 * 16), dim3(64), 0, stream, W, pw);
  hipLaunchKernelGGL(attn_pool_main, dim3(Bn * NCHUNK), dim3(256), 0, stream,
                     x, pw, bias, u, mask, outpart, sumpart);
  hipLaunchKernelGGL(finalize_kernel, dim3(Bn * 3), dim3(256), 0, stream,
                     outpart, sumpart, out);
}

// Round 11
// 137.665 us; speedup vs baseline: 2.1637x; 1.0639x over previous
//
#include <hip/hip_runtime.h>
#include <hip/hip_bf16.h>
#include <stdint.h>

// Problem constants (fixed by setup_inputs)
#define Bn 64
#define Sn 2048
#define Dn 768
#define An 256
#define EPSF 1e-7f
#define ROWS 32              // s-rows per block
#define NCHUNK (Sn / ROWS)   // 64 chunks per batch
#define NK (Dn / 32)         // 24 K-steps of 32

typedef __bf16 bf16x8 __attribute__((ext_vector_type(8)));
typedef float f32x4 __attribute__((ext_vector_type(4)));

// ---------------- pack W (fp32 row-major DxA) -> bf16 MFMA-B-fragment layout ----
// packed[( (kk*16 + cb)*64 + lane )*8 + e] = bf16( W[kk*32 + (lane>>4)*8 + e][cb*16 + (lane&15)] )
__global__ void pack_w_kernel(const float* __restrict__ W, unsigned short* __restrict__ pw) {
  int kk = blockIdx.x >> 4;     // 0..23
  int cb = blockIdx.x & 15;     // 0..15
  int l  = threadIdx.x;         // 0..63
  int a  = cb * 16 + (l & 15);
  int k0 = kk * 32 + (l >> 4) * 8;
  bf16x8 pk;
#pragma unroll
  for (int j = 0; j < 8; ++j) pk[j] = (__bf16)W[(k0 + j) * An + a];
  *(bf16x8*)(pw + ((size_t)((kk * 16 + cb) * 64 + l)) * 8) = pk;
}

// ---------------- main fused kernel (R10 + batch-issued staging loads) ----------------
// grid = 4096 (one 32-row chunk each), 256 threads = 4 waves, 3 blocks/CU.
// Staging now issues ALL 24 float4 loads per thread up front (96 VGPRs,
// pinned with sched_barrier(0)) -> ~288KB in flight per CU, saturating the
// per-CU HBM share even when co-resident blocks phase-lock. Then cvt+write.
// K-loop: W B-frags rotate through wf[4][4] (static idx): use slot kk&3,
// reload for kk+4; counted vmcnt waits hide the ~220cy L2 latency.
__launch_bounds__(256, 3)
__global__ void attn_pool_main(const float* __restrict__ x,
                               const unsigned short* __restrict__ pw,
                               const float* __restrict__ bias,
                               const float* __restrict__ u,
                               const int* __restrict__ mask,
                               float* __restrict__ outpart,
                               float* __restrict__ sumpart) {
  __shared__ __align__(16) char xs[49152];   // 32 rows x 768 bf16, XOR-swizzled
  __shared__ float aitp[128];
  __shared__ float aitv[32];

  const int tid  = threadIdx.x;
  const int lane = tid & 63;
  const int w    = tid >> 6;      // wave 0..3, cols w*64..w*64+63
  const int cid  = blockIdx.x;
  const int b    = cid >> 6;
  const int s0   = (cid & 63) * ROWS;

  float mval = 0.f;
  if (tid < 32) mval = (float)mask[(size_t)b * Sn + s0 + tid];

  // ---- stage x tile: 32 rows x 768 fp32 -> bf16 LDS (swizzled) ----
  // Phase 1: issue all 24 float4 loads (12 units x 2). Phase 2: cvt+write.
  const float* xb = x + ((size_t)b * Sn + s0) * Dn;
  {
    float4 ldA[12], ldB[12];
#pragma unroll
    for (int j = 0; j < 12; ++j) {
      int unit = tid + j * 256;       // 0..3071 ; 8 k-elems each
      int row  = unit / 96;
      int ku   = unit % 96;
      const float4* g = (const float4*)(xb + (size_t)row * Dn + ku * 8);
      ldA[j] = g[0];
      ldB[j] = g[1];
    }
    __builtin_amdgcn_sched_barrier(0);   // keep all 24 loads issued up-front
#pragma unroll
    for (int j = 0; j < 12; ++j) {
      int unit = tid + j * 256;
      int row  = unit / 96;
      int ku   = unit % 96;
      bf16x8 pk;
      pk[0] = (__bf16)ldA[j].x; pk[1] = (__bf16)ldA[j].y;
      pk[2] = (__bf16)ldA[j].z; pk[3] = (__bf16)ldA[j].w;
      pk[4] = (__bf16)ldB[j].x; pk[5] = (__bf16)ldB[j].y;
      pk[6] = (__bf16)ldB[j].z; pk[7] = (__bf16)ldB[j].w;
      int off = (row * 1536 + ku * 16) ^ ((row & 7) << 4);
      *(bf16x8*)(xs + off) = pk;
    }
  }

  const int arow  = lane & 15;
  const int kh16  = (lane >> 4) * 16;
  const int swz   = (arow & 7) << 4;
  const char* wlane = (const char*)pw + (size_t)(w * 4) * 1024 + (size_t)lane * 16;

  // ---- W pipeline prologue: load kk=0..3 into wf (ld regs dead now) ----
  bf16x8 wf[4][4];
#pragma unroll
  for (int s = 0; s < 4; ++s) {
    const char* wk = wlane + (size_t)s * 16384;
    wf[s][0] = *(const bf16x8*)(wk);
    wf[s][1] = *(const bf16x8*)(wk + 1024);
    wf[s][2] = *(const bf16x8*)(wk + 2048);
    wf[s][3] = *(const bf16x8*)(wk + 3072);
  }

  asm volatile("s_waitcnt lgkmcnt(0)" ::: "memory");
  __builtin_amdgcn_s_barrier();     // xs published; wf stream in flight

  f32x4 acc[2][4];
#pragma unroll
  for (int p = 0; p < 2; ++p)
#pragma unroll
    for (int q = 0; q < 4; ++q) acc[p][q] = (f32x4){0.f, 0.f, 0.f, 0.f};

  // ---- K-loop: use wf[kk&3], reload it for kk+4 (counted vmcnt waits) ----
#pragma unroll
  for (int kk = 0; kk < NK; ++kk) {
    const int s = kk & 3;
    bf16x8 a0 = *(const bf16x8*)(xs + ((arow * 1536 + kk * 64 + kh16) ^ swz));
    bf16x8 a1 = *(const bf16x8*)(xs + (((arow + 16) * 1536 + kk * 64 + kh16) ^ swz));
    bf16x8 b0 = wf[s][0], b1 = wf[s][1], b2 = wf[s][2], b3 = wf[s][3];
    if (kk + 4 < NK) {
      const char* wk = wlane + (size_t)(kk + 4) * 16384;
      wf[s][0] = *(const bf16x8*)(wk);
      wf[s][1] = *(const bf16x8*)(wk + 1024);
      wf[s][2] = *(const bf16x8*)(wk + 2048);
      wf[s][3] = *(const bf16x8*)(wk + 3072);
    }
    acc[0][0] = __builtin_amdgcn_mfma_f32_16x16x32_bf16(a0, b0, acc[0][0], 0, 0, 0);
    acc[1][0] = __builtin_amdgcn_mfma_f32_16x16x32_bf16(a1, b0, acc[1][0], 0, 0, 0);
    acc[0][1] = __builtin_amdgcn_mfma_f32_16x16x32_bf16(a0, b1, acc[0][1], 0, 0, 0);
    acc[1][1] = __builtin_amdgcn_mfma_f32_16x16x32_bf16(a1, b1, acc[1][1], 0, 0, 0);
    acc[0][2] = __builtin_amdgcn_mfma_f32_16x16x32_bf16(a0, b2, acc[0][2], 0, 0, 0);
    acc[1][2] = __builtin_amdgcn_mfma_f32_16x16x32_bf16(a1, b2, acc[1][2], 0, 0, 0);
    acc[0][3] = __builtin_amdgcn_mfma_f32_16x16x32_bf16(a0, b3, acc[0][3], 0, 0, 0);
    acc[1][3] = __builtin_amdgcn_mfma_f32_16x16x32_bf16(a1, b3, acc[1][3], 0, 0, 0);
  }

  // ---- epilogue: tanh + dot with u -> per-row partials ----
  float rowp[8];
#pragma unroll
  for (int p = 0; p < 8; ++p) rowp[p] = 0.f;
#pragma unroll
  for (int cbi = 0; cbi < 4; ++cbi) {
    int col = w * 64 + cbi * 16 + arow;
    float bia = bias[col];
    float uv  = u[col];
#pragma unroll
    for (int rb = 0; rb < 2; ++rb) {
#pragma unroll
      for (int r = 0; r < 4; ++r) {
        float v = acc[rb][cbi][r] + bia;
        v = fminf(fmaxf(v, -15.f), 15.f);
        float e2 = __expf(2.f * v);
        float th = (e2 - 1.f) * __builtin_amdgcn_rcpf(e2 + 1.f);
        rowp[rb * 4 + r] += th * uv;
      }
    }
  }
#pragma unroll
  for (int m = 1; m < 16; m <<= 1)
#pragma unroll
    for (int p = 0; p < 8; ++p) rowp[p] += __shfl_xor(rowp[p], m, 64);

  if (arow == 0) {
    int rbase = (lane >> 4) * 4;
#pragma unroll
    for (int rb = 0; rb < 2; ++rb)
#pragma unroll
      for (int r = 0; r < 4; ++r)
        aitp[w * 32 + rb * 16 + rbase + r] = rowp[rb * 4 + r];
  }
  __syncthreads();

  // ---- ait = exp(sum)*mask ; chunk sum ----
  if (tid < 32) {
    float s = aitp[tid] + aitp[32 + tid] + aitp[64 + tid] + aitp[96 + tid];
    float av = __expf(s) * mval;
    aitv[tid] = av;
    float t = av;
#pragma unroll
    for (int m = 1; m < 32; m <<= 1) t += __shfl_xor(t, m, 64);
    if (tid == 0) sumpart[cid] = t;
  }
  __syncthreads();

  // ---- pooling (R2-proven): 192 threads, 2 row-groups of 16 rows ----
  float pac[8];
#pragma unroll
  for (int e = 0; e < 8; ++e) pac[e] = 0.f;
  int rg = tid / 96;              // 0..1 for tid<192
  int du = tid % 96;              // 8-d unit
  if (tid < 192) {
#pragma unroll
    for (int rr = 0; rr < 16; ++rr) {
      int row = rg * 16 + rr;
      int off = (row * 1536 + du * 16) ^ ((row & 7) << 4);
      bf16x8 xv = *(const bf16x8*)(xs + off);
      float a = aitv[row];
#pragma unroll
      for (int e = 0; e < 8; ++e) pac[e] += a * (float)xv[e];
    }
  }
  __syncthreads();   // all xs reads done -> safe to overlay outred onto xs

  float* outred = (float*)xs;     // [2][768] overlay
  if (tid < 192) {
#pragma unroll
    for (int e = 0; e < 8; ++e) outred[rg * 768 + du * 8 + e] = pac[e];
  }
  __syncthreads();

  {
    float* op = outpart + (size_t)cid * Dn;
#pragma unroll
    for (int j = 0; j < 3; ++j) {
      int d = tid + j * 256;
      op[d] = outred[d] + outred[768 + d];
    }
  }
}

// ---------------- finalize: out[b,d] = sum_c outpart / (sum_c sumpart + eps) ----
// grid = 64 b x 3 slabs of 256 d
__global__ void finalize_kernel(const float* __restrict__ outpart,
                                const float* __restrict__ sumpart,
                                float* __restrict__ out) {
  __shared__ float sh;
  int b = blockIdx.x / 3, slab = blockIdx.x % 3;
  int tid = threadIdx.x;
  if (tid < 64) {
    float v = sumpart[b * 64 + tid];
#pragma unroll
    for (int m = 1; m < 64; m <<= 1) v += __shfl_xor(v, m, 64);
    if (tid == 0) sh = v + EPSF;
  }
  __syncthreads();
  float inv = 1.0f / sh;
  int d = slab * 256 + tid;
  const float* p = outpart + (size_t)b * 64 * Dn + d;
  float s = 0.f;
#pragma unroll 8
  for (int c = 0; c < 64; ++c) s += p[(size_t)c * Dn];
  out[b * Dn + d] = s * inv;
}

extern "C" void kernel_launch(void* const* d_in, const int* in_sizes, int n_in,
                              void* d_out, int out_size, void* d_ws, size_t ws_size,
                              hipStream_t stream) {
  const float* x    = (const float*)d_in[0];
  const float* W    = (const float*)d_in[1];
  const float* bias = (const float*)d_in[2];
  const float* u    = (const float*)d_in[3];
  const int*   mask = (const int*)d_in[4];
  float* out = (float*)d_out;

  unsigned short* pw = (unsigned short*)d_ws;                      // 393216 B
  float* outpart = (float*)((char*)d_ws + 393216);                 // 64*64*768*4 = 12.58 MB
  float* sumpart = (float*)((char*)d_ws + 393216 + 12582912);      // 16 KB

  hipLaunchKernelGGL(pack_w_kernel, dim3(24 * 16), dim3(64), 0, stream, W, pw);
  hipLaunchKernelGGL(attn_pool_main, dim3(Bn * NCHUNK), dim3(256), 0, stream,
                     x, pw, bias, u, mask, outpart, sumpart);
  hipLaunchKernelGGL(finalize_kernel, dim3(Bn * 3), dim3(256), 0, stream,
                     outpart, sumpart, out);
}